// Round 1
// baseline (338.788 us; speedup 1.0000x reference)
//
#include <hip/hip_runtime.h>
#include <stdint.h>

// Problem constants
#define S_LEN 2048
#define EMB   1024
#define NH    16
#define HD    64
// GEMM tiling
#define BM 128
#define BN 128
#define BK 64

typedef __bf16 bf16x8 __attribute__((ext_vector_type(8)));
typedef float  floatx4 __attribute__((ext_vector_type(4)));

__device__ __forceinline__ unsigned short f2bf(float f) {
  unsigned u = __builtin_bit_cast(unsigned, f);
  u += 0x7fffu + ((u >> 16) & 1u);   // RNE
  return (unsigned short)(u >> 16);
}

// fp32 -> bf16, 4 elems/thread
__global__ __launch_bounds__(256) void cvt_bf16(const float* __restrict__ src,
                                                unsigned short* __restrict__ dst, int n) {
  int i = (blockIdx.x * 256 + threadIdx.x) * 4;
  if (i >= n) return;
  float4 v = *(const float4*)(src + i);
  ushort4 o;
  o.x = f2bf(v.x); o.y = f2bf(v.y); o.z = f2bf(v.z); o.w = f2bf(v.w);
  *(ushort4*)(dst + i) = o;
}

// async global->LDS 16B; LDS dest is wave-uniform base + lane*16
__device__ __forceinline__ void stage16(const void* g, void* l) {
  __builtin_amdgcn_global_load_lds(
      (const __attribute__((address_space(1))) void*)g,
      (__attribute__((address_space(3))) void*)l, 16, 0, 0);
}

// C = A[4096xK] * Bm[1024xK]^T + bias, bf16 inputs, fp32 accum.
// mode 0: fp32 row-major out [4096][1024]
// mode 1: bf16 out scattered to [B,H,S,D]
// mode 2: bf16 out scattered to [B,H,D,S] (transposed V)
__device__ __forceinline__ void gemm128(const unsigned short* __restrict__ A,
                                        const unsigned short* __restrict__ Bm,
                                        const float* __restrict__ bias,
                                        void* __restrict__ outp, int mode,
                                        unsigned short* As, unsigned short* Bs) {
  const int tid  = threadIdx.x;
  const int lane = tid & 63;
  const int wave = tid >> 6;
  const int m16  = lane & 15;
  const int quad = lane >> 4;
  const int m0 = blockIdx.x * BM;
  const int n0 = blockIdx.y * BN;
  const int wrow = (wave >> 1) * 64;
  const int wcol = (wave & 1) * 64;
  const int K = 1024, N = 1024;

  floatx4 acc[4][4];
  for (int i = 0; i < 4; ++i)
    for (int j = 0; j < 4; ++j) acc[i][j] = floatx4{0.f, 0.f, 0.f, 0.f};

  for (int k0 = 0; k0 < K; k0 += BK) {
    __syncthreads();  // previous compute done before restaging
    // 128x64 bf16 tile = 16KB = 1024 chunks of 16B; 4 chunks/thread
    for (int i = 0; i < 4; ++i) {
      int c   = i * 256 + tid;
      int row = c >> 3;            // 8 chunks per 64-elem row
      int col = (c & 7) << 3;
      const unsigned short* ga = A  + (size_t)(m0 + row) * K + k0 + col;
      const unsigned short* gb = Bm + (size_t)(n0 + row) * K + k0 + col;
      char* la = (char*)As + (size_t)(i * 256 + wave * 64) * 16;  // wave-uniform base
      char* lb = (char*)Bs + (size_t)(i * 256 + wave * 64) * 16;
      stage16(ga, la);
      stage16(gb, lb);
    }
    __syncthreads();  // drains vmcnt(0) -> LDS tiles complete
    for (int kk = 0; kk < 2; ++kk) {
      bf16x8 af[4], bfr[4];
      for (int ti = 0; ti < 4; ++ti)
        af[ti] = *(const bf16x8*)(As + (wrow + ti * 16 + m16) * BK + kk * 32 + quad * 8);
      for (int tj = 0; tj < 4; ++tj)
        bfr[tj] = *(const bf16x8*)(Bs + (wcol + tj * 16 + m16) * BK + kk * 32 + quad * 8);
      for (int ti = 0; ti < 4; ++ti)
        for (int tj = 0; tj < 4; ++tj)
          acc[ti][tj] = __builtin_amdgcn_mfma_f32_16x16x32_bf16(af[ti], bfr[tj], acc[ti][tj], 0, 0, 0);
    }
  }

  for (int tj = 0; tj < 4; ++tj) {
    int n = n0 + wcol + tj * 16 + m16;
    float bv = bias[n];
    for (int ti = 0; ti < 4; ++ti) {
      for (int reg = 0; reg < 4; ++reg) {
        int m = m0 + wrow + ti * 16 + quad * 4 + reg;   // C row = quad*4+reg, col = lane&15
        float v = acc[ti][tj][reg] + bv;
        if (mode == 0) {
          ((float*)outp)[(size_t)m * N + n] = v;
        } else {
          int b = m >> 11, s = m & 2047, hh = n >> 6, d = n & 63;
          unsigned short bb = f2bf(v);
          if (mode == 1)
            ((unsigned short*)outp)[((size_t)(b * NH + hh) * S_LEN + s) * HD + d] = bb;
          else
            ((unsigned short*)outp)[((size_t)(b * NH + hh) * HD + d) * S_LEN + s] = bb;
        }
      }
    }
  }
}

__global__ __launch_bounds__(256) void qkv_gemm(const unsigned short* __restrict__ xb,
                                                const unsigned short* __restrict__ Wqb,
                                                const unsigned short* __restrict__ Wkb,
                                                const unsigned short* __restrict__ Wvb,
                                                const float* __restrict__ bq,
                                                const float* __restrict__ bk,
                                                const float* __restrict__ bv,
                                                unsigned short* __restrict__ Qb,
                                                unsigned short* __restrict__ Kb,
                                                unsigned short* __restrict__ Vtb) {
  __shared__ unsigned short As[BM * BK];
  __shared__ unsigned short Bs[BN * BK];
  int z = blockIdx.z;
  const unsigned short* Bm = (z == 0) ? Wqb : (z == 1) ? Wkb : Wvb;
  const float* bias        = (z == 0) ? bq  : (z == 1) ? bk  : bv;
  unsigned short* outp     = (z == 0) ? Qb  : (z == 1) ? Kb  : Vtb;
  gemm128(xb, Bm, bias, outp, (z == 2) ? 2 : 1, As, Bs);
}

__global__ __launch_bounds__(256) void out_gemm(const unsigned short* __restrict__ Ab,
                                                const unsigned short* __restrict__ Wob,
                                                const float* __restrict__ bo,
                                                float* __restrict__ out) {
  __shared__ unsigned short As[BM * BK];
  __shared__ unsigned short Bs[BN * BK];
  gemm128(Ab, Wob, bo, out, 0, As, Bs);
}

// Flash attention: one block per (64-row q-tile, b*h). 4 waves; wave w owns q rows 16w..16w+15.
__global__ __launch_bounds__(256) void attn_kernel(const unsigned short* __restrict__ Qb,  // [B,H,S,D]
                                                   const unsigned short* __restrict__ Kb,  // [B,H,S,D]
                                                   const unsigned short* __restrict__ Vtb, // [B,H,D,S]
                                                   const int* __restrict__ mask,           // [B,S]
                                                   unsigned short* __restrict__ attnb) {   // [B,S,E]
  __shared__ unsigned short Qs[64 * 72];   // stride 72 bf16 = 144B (16B-aligned rows)
  __shared__ unsigned short Ks[64 * 72];
  __shared__ unsigned short Vts[64 * 72];  // [d][kv]
  __shared__ unsigned short Ps[64 * 72];   // P in A-operand layout (row-major q x kv)
  __shared__ float Sfp[64 * 66];
  __shared__ float red[64 * 4];
  __shared__ float mrow[64], lrow[64], arow[64], mbias[64];

  const int tid  = threadIdx.x;
  const int lane = tid & 63;
  const int wave = tid >> 6;
  const int m16  = lane & 15;
  const int quad = lane >> 4;
  const int qt = blockIdx.x;   // 0..31
  const int bh = blockIdx.y;   // 0..31
  const int b  = bh >> 4;
  const int h  = bh & 15;
  const int q0 = qt * 64;

  const size_t head = (size_t)bh * S_LEN * HD;

  // stage Q tile (once): 512 x 16B chunks
  for (int i = 0; i < 2; ++i) {
    int c = i * 256 + tid;
    int row = c >> 3, dch = (c & 7) << 3;
    uint4 v = *(const uint4*)(Qb + head + (size_t)(q0 + row) * HD + dch);
    *(uint4*)&Qs[row * 72 + dch] = v;
  }
  if (tid < 64) { mrow[tid] = -1e30f; lrow[tid] = 0.f; }

  floatx4 acc_o[4];
  for (int tj = 0; tj < 4; ++tj) acc_o[tj] = floatx4{0.f, 0.f, 0.f, 0.f};

  const int r = tid >> 2;          // softmax: thread group of 4 per row
  const int sub = tid & 3;
  const int cbase = sub * 16;

  for (int kb = 0; kb < 32; ++kb) {
    const int kv0 = kb * 64;
    __syncthreads();  // previous PV reads of Ks/Vts done
    for (int i = 0; i < 2; ++i) {
      int c = i * 256 + tid;
      int row = c >> 3, dch = (c & 7) << 3;
      uint4 kv = *(const uint4*)(Kb + head + (size_t)(kv0 + row) * HD + dch);
      *(uint4*)&Ks[row * 72 + dch] = kv;
      uint4 vv = *(const uint4*)(Vtb + head + (size_t)row * S_LEN + kv0 + dch); // row=d, dch=kv off
      *(uint4*)&Vts[row * 72 + dch] = vv;
    }
    if (tid < 64) mbias[tid] = (mask[b * S_LEN + kv0 + tid] == 0) ? -1e9f : 0.f;
    __syncthreads();

    // S = Q K^T (per wave: 16 q-rows x 64 kv-cols)
    floatx4 acc_s[4];
    for (int tj = 0; tj < 4; ++tj) acc_s[tj] = floatx4{0.f, 0.f, 0.f, 0.f};
    for (int kk = 0; kk < 2; ++kk) {
      bf16x8 aq = *(const bf16x8*)&Qs[(wave * 16 + m16) * 72 + kk * 32 + quad * 8];
      for (int tj = 0; tj < 4; ++tj) {
        bf16x8 bk8 = *(const bf16x8*)&Ks[(tj * 16 + m16) * 72 + kk * 32 + quad * 8];
        acc_s[tj] = __builtin_amdgcn_mfma_f32_16x16x32_bf16(aq, bk8, acc_s[tj], 0, 0, 0);
      }
    }
    for (int tj = 0; tj < 4; ++tj)
      for (int reg = 0; reg < 4; ++reg)
        Sfp[(wave * 16 + quad * 4 + reg) * 66 + tj * 16 + m16] = acc_s[tj][reg];
    __syncthreads();

    // online softmax
    float mloc = -1e30f;
    for (int i = 0; i < 16; ++i) {
      int c = cbase + i;
      float s = Sfp[r * 66 + c] * 0.125f + mbias[c];
      Sfp[r * 66 + c] = s;
      mloc = fmaxf(mloc, s);
    }
    red[r * 4 + sub] = mloc;
    __syncthreads();
    if (tid < 64) {
      float mo = mrow[tid];
      float mn = fmaxf(fmaxf(red[tid * 4], red[tid * 4 + 1]),
                       fmaxf(red[tid * 4 + 2], red[tid * 4 + 3]));
      mn = fmaxf(mo, mn);
      arow[tid] = __expf(mo - mn);
      mrow[tid] = mn;
    }
    __syncthreads();
    float sloc = 0.f;
    float mr = mrow[r];
    for (int i = 0; i < 16; ++i) {
      int c = cbase + i;
      float p = __expf(Sfp[r * 66 + c] - mr);
      Ps[r * 72 + c] = f2bf(p);
      sloc += p;
    }
    red[r * 4 + sub] = sloc;
    __syncthreads();
    if (tid < 64)
      lrow[tid] = lrow[tid] * arow[tid] + red[tid * 4] + red[tid * 4 + 1] + red[tid * 4 + 2] + red[tid * 4 + 3];
    __syncthreads();  // Ps + arow visible to all

    // rescale O, then O += P V
    float al[4];
    for (int reg = 0; reg < 4; ++reg) al[reg] = arow[wave * 16 + quad * 4 + reg];
    for (int tj = 0; tj < 4; ++tj)
      for (int reg = 0; reg < 4; ++reg) acc_o[tj][reg] *= al[reg];
    for (int kk = 0; kk < 2; ++kk) {
      bf16x8 ap = *(const bf16x8*)&Ps[(wave * 16 + m16) * 72 + kk * 32 + quad * 8];
      for (int tj = 0; tj < 4; ++tj) {
        bf16x8 bv8 = *(const bf16x8*)&Vts[(tj * 16 + m16) * 72 + kk * 32 + quad * 8];
        acc_o[tj] = __builtin_amdgcn_mfma_f32_16x16x32_bf16(ap, bv8, acc_o[tj], 0, 0, 0);
      }
    }
  }

  __syncthreads();
  for (int reg = 0; reg < 4; ++reg) {
    int rr = wave * 16 + quad * 4 + reg;
    float rl = 1.f / lrow[rr];
    int srow = q0 + rr;
    for (int tj = 0; tj < 4; ++tj) {
      int e = h * HD + tj * 16 + m16;
      attnb[((size_t)(b * S_LEN + srow)) * EMB + e] = f2bf(acc_o[tj][reg] * rl);
    }
  }
}

extern "C" void kernel_launch(void* const* d_in, const int* in_sizes, int n_in,
                              void* d_out, int out_size, void* d_ws, size_t ws_size,
                              hipStream_t stream) {
  const float* x  = (const float*)d_in[0];
  const int* mask = (const int*)d_in[1];
  const float* Wq = (const float*)d_in[2];
  const float* bq = (const float*)d_in[3];
  const float* Wk = (const float*)d_in[4];
  const float* bk = (const float*)d_in[5];
  const float* Wv = (const float*)d_in[6];
  const float* bv = (const float*)d_in[7];
  const float* Wo = (const float*)d_in[8];
  const float* bo = (const float*)d_in[9];
  float* out = (float*)d_out;

  char* ws = (char*)d_ws;
  unsigned short* xb  = (unsigned short*)(ws);               // 8 MB  [4096][1024]
  unsigned short* Wqb = (unsigned short*)(ws + 8388608);     // 2 MB
  unsigned short* Wkb = (unsigned short*)(ws + 10485760);    // 2 MB
  unsigned short* Wvb = (unsigned short*)(ws + 12582912);    // 2 MB
  unsigned short* Wob = (unsigned short*)(ws + 14680064);    // 2 MB
  unsigned short* Qb  = (unsigned short*)(ws + 16777216);    // 8 MB  [B,H,S,D]
  unsigned short* Kbb = (unsigned short*)(ws + 25165824);    // 8 MB  [B,H,S,D]
  unsigned short* Vtb = (unsigned short*)(ws + 33554432);    // 8 MB  [B,H,D,S]
  unsigned short* Ab  = (unsigned short*)(ws + 41943040);    // 8 MB  [B,S,E]

  cvt_bf16<<<dim3(4096), dim3(256), 0, stream>>>(x, xb, 4194304);
  cvt_bf16<<<dim3(1024), dim3(256), 0, stream>>>(Wq, Wqb, 1048576);
  cvt_bf16<<<dim3(1024), dim3(256), 0, stream>>>(Wk, Wkb, 1048576);
  cvt_bf16<<<dim3(1024), dim3(256), 0, stream>>>(Wv, Wvb, 1048576);
  cvt_bf16<<<dim3(1024), dim3(256), 0, stream>>>(Wo, Wob, 1048576);

  qkv_gemm<<<dim3(32, 8, 3), dim3(256), 0, stream>>>(xb, Wqb, Wkb, Wvb, bq, bk, bv, Qb, Kbb, Vtb);
  attn_kernel<<<dim3(32, 32), dim3(256), 0, stream>>>(Qb, Kbb, Vtb, mask, Ab);
  out_gemm<<<dim3(32, 8), dim3(256), 0, stream>>>(Ab, Wob, bo, out);
}

// Round 2
// 270.295 us; speedup vs baseline: 1.2534x; 1.2534x over previous
//
#include <hip/hip_runtime.h>
#include <stdint.h>

#define S_LEN 2048
#define EMB   1024
#define NH    16
#define HD    64
#define BM 128
#define BN 128
#define BK 64

typedef __bf16 bf16x8 __attribute__((ext_vector_type(8)));
typedef short  short4v __attribute__((ext_vector_type(4)));
typedef float  floatx4 __attribute__((ext_vector_type(4)));

#if defined(__has_builtin)
#if __has_builtin(__builtin_amdgcn_mfma_f32_16x16x16bf16_1k)
#define HAVE_MFMA16 1
#endif
#endif

__device__ __forceinline__ unsigned short f2bf(float f) {
  unsigned u = __builtin_bit_cast(unsigned, f);
  u += 0x7fffu + ((u >> 16) & 1u);   // RNE
  return (unsigned short)(u >> 16);
}

// Fused fp32->bf16 for x + 4 weights (one launch instead of 5)
__global__ __launch_bounds__(256) void cvt_all(const float* __restrict__ x,
                                               const float* __restrict__ Wq,
                                               const float* __restrict__ Wk,
                                               const float* __restrict__ Wv,
                                               const float* __restrict__ Wo,
                                               unsigned short* __restrict__ xb,
                                               unsigned short* __restrict__ Wqb,
                                               unsigned short* __restrict__ Wkb,
                                               unsigned short* __restrict__ Wvb,
                                               unsigned short* __restrict__ Wob) {
  int blk = blockIdx.x;
  const float* s; unsigned short* d; int off;
  if (blk < 4096)      { s = x;  d = xb;  off = blk; }
  else if (blk < 5120) { s = Wq; d = Wqb; off = blk - 4096; }
  else if (blk < 6144) { s = Wk; d = Wkb; off = blk - 5120; }
  else if (blk < 7168) { s = Wv; d = Wvb; off = blk - 6144; }
  else                 { s = Wo; d = Wob; off = blk - 7168; }
  int i = (off * 256 + threadIdx.x) * 4;
  float4 v = *(const float4*)(s + i);
  ushort4 o;
  o.x = f2bf(v.x); o.y = f2bf(v.y); o.z = f2bf(v.z); o.w = f2bf(v.w);
  *(ushort4*)(d + i) = o;
}

__device__ __forceinline__ void stage16(const void* g, void* l) {
  __builtin_amdgcn_global_load_lds(
      (const __attribute__((address_space(1))) void*)g,
      (__attribute__((address_space(3))) void*)l, 16, 0, 0);
}

// C = A[4096xK] * Bm[1024xK]^T + bias, bf16 in, fp32 accum; result * scale.
// mode 0: fp32 row-major [4096][1024]; mode 1: bf16 [B,H,S,D]; mode 2: bf16 [B,H,D,S]
__device__ __forceinline__ void gemm128(const unsigned short* __restrict__ A,
                                        const unsigned short* __restrict__ Bm,
                                        const float* __restrict__ bias, float scale,
                                        void* __restrict__ outp, int mode,
                                        unsigned short* As, unsigned short* Bs) {
  const int tid  = threadIdx.x;
  const int lane = tid & 63;
  const int wave = tid >> 6;
  const int m16  = lane & 15;
  const int quad = lane >> 4;
  const int m0 = blockIdx.x * BM;
  const int n0 = blockIdx.y * BN;
  const int wrow = (wave >> 1) * 64;
  const int wcol = (wave & 1) * 64;
  const int K = 1024, N = 1024;

  floatx4 acc[4][4];
  for (int i = 0; i < 4; ++i)
    for (int j = 0; j < 4; ++j) acc[i][j] = floatx4{0.f, 0.f, 0.f, 0.f};

  for (int k0 = 0; k0 < K; k0 += BK) {
    __syncthreads();
    for (int i = 0; i < 4; ++i) {
      int c   = i * 256 + tid;
      int row = c >> 3;
      int col = (c & 7) << 3;
      const unsigned short* ga = A  + (size_t)(m0 + row) * K + k0 + col;
      const unsigned short* gb = Bm + (size_t)(n0 + row) * K + k0 + col;
      char* la = (char*)As + (size_t)(i * 256 + wave * 64) * 16;
      char* lb = (char*)Bs + (size_t)(i * 256 + wave * 64) * 16;
      stage16(ga, la);
      stage16(gb, lb);
    }
    __syncthreads();
    for (int kk = 0; kk < 2; ++kk) {
      bf16x8 af[4], bfr[4];
      for (int ti = 0; ti < 4; ++ti)
        af[ti] = *(const bf16x8*)(As + (wrow + ti * 16 + m16) * BK + kk * 32 + quad * 8);
      for (int tj = 0; tj < 4; ++tj)
        bfr[tj] = *(const bf16x8*)(Bs + (wcol + tj * 16 + m16) * BK + kk * 32 + quad * 8);
      for (int ti = 0; ti < 4; ++ti)
        for (int tj = 0; tj < 4; ++tj)
          acc[ti][tj] = __builtin_amdgcn_mfma_f32_16x16x32_bf16(af[ti], bfr[tj], acc[ti][tj], 0, 0, 0);
    }
  }

  for (int tj = 0; tj < 4; ++tj) {
    int n = n0 + wcol + tj * 16 + m16;
    float bv = bias[n];
    for (int ti = 0; ti < 4; ++ti) {
      for (int reg = 0; reg < 4; ++reg) {
        int m = m0 + wrow + ti * 16 + quad * 4 + reg;
        float v = (acc[ti][tj][reg] + bv) * scale;
        if (mode == 0) {
          ((float*)outp)[(size_t)m * N + n] = v;
        } else {
          int b = m >> 11, s = m & 2047, hh = n >> 6, d = n & 63;
          unsigned short bb = f2bf(v);
          if (mode == 1)
            ((unsigned short*)outp)[((size_t)(b * NH + hh) * S_LEN + s) * HD + d] = bb;
          else
            ((unsigned short*)outp)[((size_t)(b * NH + hh) * HD + d) * S_LEN + s] = bb;
        }
      }
    }
  }
}

__global__ __launch_bounds__(256) void qkv_gemm(const unsigned short* __restrict__ xb,
                                                const unsigned short* __restrict__ Wqb,
                                                const unsigned short* __restrict__ Wkb,
                                                const unsigned short* __restrict__ Wvb,
                                                const float* __restrict__ bq,
                                                const float* __restrict__ bk,
                                                const float* __restrict__ bv,
                                                unsigned short* __restrict__ Qb,
                                                unsigned short* __restrict__ Kb,
                                                unsigned short* __restrict__ Vtb) {
  __shared__ unsigned short As[BM * BK];
  __shared__ unsigned short Bs[BN * BK];
  int z = blockIdx.z;
  const unsigned short* Bm = (z == 0) ? Wqb : (z == 1) ? Wkb : Wvb;
  const float* bias        = (z == 0) ? bq  : (z == 1) ? bk  : bv;
  unsigned short* outp     = (z == 0) ? Qb  : (z == 1) ? Kb  : Vtb;
  // fold softmax 1/sqrt(64)=0.125 into Q projection (exact in fp32)
  float scale = (z == 0) ? 0.125f : 1.0f;
  gemm128(xb, Bm, bias, scale, outp, (z == 2) ? 2 : 1, As, Bs);
}

__global__ __launch_bounds__(256) void out_gemm(const unsigned short* __restrict__ Ab,
                                                const unsigned short* __restrict__ Wob,
                                                const float* __restrict__ bo,
                                                float* __restrict__ out) {
  __shared__ unsigned short As[BM * BK];
  __shared__ unsigned short Bs[BN * BK];
  gemm128(Ab, Wob, bo, 1.0f, out, 0, As, Bs);
}

// Flash attention v2: S^T = K Q^T so softmax is in-register (col=q layout).
// One block = 64 q-rows x one (b,h). Wave w owns q = q0 + w*16 + (lane&15).
// Barriers only around K/V staging: 2 per kv-tile.
__global__ __launch_bounds__(256, 4) void attn_kernel(const unsigned short* __restrict__ Qb,  // [B,H,S,D] (pre-scaled by 0.125)
                                                      const unsigned short* __restrict__ Kb,  // [B,H,S,D]
                                                      const unsigned short* __restrict__ Vtb, // [B,H,D,S]
                                                      const int* __restrict__ mask,           // [B,S]
                                                      unsigned short* __restrict__ attnb) {   // [B,S,E]
  __shared__ unsigned short Ks[64 * 72];   // [kv][d], stride 72 (2-way bank alias: free)
  __shared__ unsigned short Vts[64 * 72];  // [d][kv]
  __shared__ float mb[64];
#ifndef HAVE_MFMA16
  __shared__ unsigned short Pq[4 * 16 * 72];  // per-wave P [q][kv] for x32 fallback
#endif

  const int tid  = threadIdx.x;
  const int lane = tid & 63;
  const int wave = tid >> 6;
  const int m16  = lane & 15;
  const int quad = lane >> 4;
  const int qt = blockIdx.x;
  const int bh = blockIdx.y;
  const int b  = bh >> 4;
  const int h  = bh & 15;
  const int q0 = qt * 64;
  const size_t head = (size_t)bh * S_LEN * HD;

  // Q fragment straight to registers (B-operand: n=q=m16, k=d=kk*32+quad*8+j)
  bf16x8 qf[2];
  {
    const unsigned short* qrow = Qb + head + (size_t)(q0 + wave * 16 + m16) * HD;
    qf[0] = *(const bf16x8*)(qrow + quad * 8);
    qf[1] = *(const bf16x8*)(qrow + 32 + quad * 8);
  }

  float m_run = -1e30f, l_run = 0.f;
  floatx4 acc_o[4];   // O^T[d = ti*16+quad*4+reg][q = m16]
  for (int ti = 0; ti < 4; ++ti) acc_o[ti] = floatx4{0.f, 0.f, 0.f, 0.f};

  for (int kb = 0; kb < 32; ++kb) {
    const int kv0 = kb * 64;
    __syncthreads();  // prior PV reads of Ks/Vts complete
    for (int i = 0; i < 2; ++i) {
      int c = i * 256 + tid;
      int row = c >> 3, dch = (c & 7) << 3;
      uint4 kv = *(const uint4*)(Kb + head + (size_t)(kv0 + row) * HD + dch);
      *(uint4*)&Ks[row * 72 + dch] = kv;
      uint4 vv = *(const uint4*)(Vtb + head + (size_t)row * S_LEN + kv0 + dch);
      *(uint4*)&Vts[row * 72 + dch] = vv;
    }
    if (tid < 64) mb[tid] = (mask[b * S_LEN + kv0 + tid] == 0) ? -1e9f : 0.f;
    __syncthreads();

    // S^T[kv][q]: A = K frag (m=kv), B = Q frag (n=q)
    floatx4 acc_s[4];
    for (int tj = 0; tj < 4; ++tj) acc_s[tj] = floatx4{0.f, 0.f, 0.f, 0.f};
    for (int kk = 0; kk < 2; ++kk) {
      for (int tj = 0; tj < 4; ++tj) {
        bf16x8 kf = *(const bf16x8*)&Ks[(tj * 16 + m16) * 72 + kk * 32 + quad * 8];
        acc_s[tj] = __builtin_amdgcn_mfma_f32_16x16x32_bf16(kf, qf[kk], acc_s[tj], 0, 0, 0);
      }
    }

    // in-register online softmax over kv (rows of S^T = regs + quads)
    float s[16];
    for (int t = 0; t < 4; ++t) {
      float4 mv = *(const float4*)&mb[t * 16 + quad * 4];   // broadcast within quad
      s[t * 4 + 0] = acc_s[t][0] + mv.x;
      s[t * 4 + 1] = acc_s[t][1] + mv.y;
      s[t * 4 + 2] = acc_s[t][2] + mv.z;
      s[t * 4 + 3] = acc_s[t][3] + mv.w;
    }
    float mloc = s[0];
    for (int i = 1; i < 16; ++i) mloc = fmaxf(mloc, s[i]);
    mloc = fmaxf(mloc, __shfl_xor(mloc, 16));
    mloc = fmaxf(mloc, __shfl_xor(mloc, 32));
    float mnew = fmaxf(m_run, mloc);
    float alpha = __expf(m_run - mnew);
    m_run = mnew;

    unsigned short pb[16];
    float sl = 0.f;
    for (int i = 0; i < 16; ++i) {
      float p = __expf(s[i] - mnew);
      sl += p;
      pb[i] = f2bf(p);
    }
    sl += __shfl_xor(sl, 16);
    sl += __shfl_xor(sl, 32);
    l_run = l_run * alpha + sl;

    for (int ti = 0; ti < 4; ++ti)
      for (int reg = 0; reg < 4; ++reg) acc_o[ti][reg] *= alpha;

#ifdef HAVE_MFMA16
    // P already in B-operand layout of 16x16x16 (n=q=m16, k=kv=quad*4+j = C regs)
    short4v Pb[4];
    for (int c = 0; c < 4; ++c) {
      short4v t;
      t[0] = (short)pb[c * 4 + 0]; t[1] = (short)pb[c * 4 + 1];
      t[2] = (short)pb[c * 4 + 2]; t[3] = (short)pb[c * 4 + 3];
      Pb[c] = t;
    }
    for (int ti = 0; ti < 4; ++ti) {
      for (int c = 0; c < 4; ++c) {
        short4v vf = *(const short4v*)&Vts[(ti * 16 + m16) * 72 + c * 16 + quad * 4];
        acc_o[ti] = __builtin_amdgcn_mfma_f32_16x16x16bf16_1k(vf, Pb[c], acc_o[ti], 0, 0, 0);
      }
    }
#else
    // fallback: per-wave LDS round-trip + x32 (no inter-wave hazard -> no barrier)
    unsigned short* Pw = Pq + wave * 16 * 72;
    for (int t = 0; t < 4; ++t) {
      unsigned lo = (unsigned)pb[t * 4 + 0] | ((unsigned)pb[t * 4 + 1] << 16);
      unsigned hi = (unsigned)pb[t * 4 + 2] | ((unsigned)pb[t * 4 + 3] << 16);
      *(unsigned*)&Pw[m16 * 72 + t * 16 + quad * 4]     = lo;
      *(unsigned*)&Pw[m16 * 72 + t * 16 + quad * 4 + 2] = hi;
    }
    for (int kk = 0; kk < 2; ++kk) {
      bf16x8 pf = *(const bf16x8*)&Pw[m16 * 72 + kk * 32 + quad * 8];
      for (int ti = 0; ti < 4; ++ti) {
        bf16x8 vf = *(const bf16x8*)&Vts[(ti * 16 + m16) * 72 + kk * 32 + quad * 8];
        acc_o[ti] = __builtin_amdgcn_mfma_f32_16x16x32_bf16(vf, pf, acc_o[ti], 0, 0, 0);
      }
    }
#endif
  }

  float rl = 1.f / l_run;
  int srow = q0 + wave * 16 + m16;
  for (int ti = 0; ti < 4; ++ti) {
    ushort4 o;
    o.x = f2bf(acc_o[ti][0] * rl);
    o.y = f2bf(acc_o[ti][1] * rl);
    o.z = f2bf(acc_o[ti][2] * rl);
    o.w = f2bf(acc_o[ti][3] * rl);
    int e = h * HD + ti * 16 + quad * 4;
    *(ushort4*)&attnb[((size_t)(b * S_LEN + srow)) * EMB + e] = o;
  }
}

extern "C" void kernel_launch(void* const* d_in, const int* in_sizes, int n_in,
                              void* d_out, int out_size, void* d_ws, size_t ws_size,
                              hipStream_t stream) {
  const float* x  = (const float*)d_in[0];
  const int* mask = (const int*)d_in[1];
  const float* Wq = (const float*)d_in[2];
  const float* bq = (const float*)d_in[3];
  const float* Wk = (const float*)d_in[4];
  const float* bk = (const float*)d_in[5];
  const float* Wv = (const float*)d_in[6];
  const float* bv = (const float*)d_in[7];
  const float* Wo = (const float*)d_in[8];
  const float* bo = (const float*)d_in[9];
  float* out = (float*)d_out;

  char* ws = (char*)d_ws;
  unsigned short* xb  = (unsigned short*)(ws);               // 8 MB
  unsigned short* Wqb = (unsigned short*)(ws + 8388608);     // 2 MB
  unsigned short* Wkb = (unsigned short*)(ws + 10485760);    // 2 MB
  unsigned short* Wvb = (unsigned short*)(ws + 12582912);    // 2 MB
  unsigned short* Wob = (unsigned short*)(ws + 14680064);    // 2 MB
  unsigned short* Qb  = (unsigned short*)(ws + 16777216);    // 8 MB [B,H,S,D]
  unsigned short* Kbb = (unsigned short*)(ws + 25165824);    // 8 MB [B,H,S,D]
  unsigned short* Vtb = (unsigned short*)(ws + 33554432);    // 8 MB [B,H,D,S]
  unsigned short* Ab  = (unsigned short*)(ws + 41943040);    // 8 MB [B,S,E]

  cvt_all<<<dim3(8192), dim3(256), 0, stream>>>(x, Wq, Wk, Wv, Wo, xb, Wqb, Wkb, Wvb, Wob);
  qkv_gemm<<<dim3(32, 8, 3), dim3(256), 0, stream>>>(xb, Wqb, Wkb, Wvb, bq, bk, bv, Qb, Kbb, Vtb);
  attn_kernel<<<dim3(32, 32), dim3(256), 0, stream>>>(Qb, Kbb, Vtb, mask, Ab);
  out_gemm<<<dim3(32, 8), dim3(256), 0, stream>>>(Ab, Wob, bo, out);
}

// Round 3
// 246.961 us; speedup vs baseline: 1.3718x; 1.0945x over previous
//
#include <hip/hip_runtime.h>
#include <stdint.h>

#define S_LEN 2048
#define EMB   1024
#define NH    16
#define HD    64
#define BM 128
#define BN 128
#define BK 64

typedef __bf16 bf16x8 __attribute__((ext_vector_type(8)));
typedef short  short4v __attribute__((ext_vector_type(4)));
typedef unsigned int uint2v __attribute__((ext_vector_type(2)));
typedef float  floatx4 __attribute__((ext_vector_type(4)));

#if defined(__has_builtin)
#if __has_builtin(__builtin_amdgcn_mfma_f32_16x16x16bf16_1k)
#define HAVE_MFMA16 1
#endif
#if __has_builtin(__builtin_amdgcn_exp2f)
#define EXP2F(x) __builtin_amdgcn_exp2f(x)
#endif
#endif
#ifndef EXP2F
#define EXP2F(x) exp2f(x)
#endif

// 0.125 (1/sqrt(64)) * log2(e): Q pre-scale so softmax runs in exp2 domain
#define QSCALE 0.1803368801111204f

__device__ __forceinline__ unsigned short f2bf(float f) {
  unsigned u = __builtin_bit_cast(unsigned, f);
  u += 0x7fffu + ((u >> 16) & 1u);   // RNE
  return (unsigned short)(u >> 16);
}

__global__ __launch_bounds__(256) void cvt_all(const float* __restrict__ x,
                                               const float* __restrict__ Wq,
                                               const float* __restrict__ Wk,
                                               const float* __restrict__ Wv,
                                               const float* __restrict__ Wo,
                                               unsigned short* __restrict__ xb,
                                               unsigned short* __restrict__ Wqb,
                                               unsigned short* __restrict__ Wkb,
                                               unsigned short* __restrict__ Wvb,
                                               unsigned short* __restrict__ Wob) {
  int blk = blockIdx.x;
  const float* s; unsigned short* d; int off;
  if (blk < 4096)      { s = x;  d = xb;  off = blk; }
  else if (blk < 5120) { s = Wq; d = Wqb; off = blk - 4096; }
  else if (blk < 6144) { s = Wk; d = Wkb; off = blk - 5120; }
  else if (blk < 7168) { s = Wv; d = Wvb; off = blk - 6144; }
  else                 { s = Wo; d = Wob; off = blk - 7168; }
  int i = (off * 256 + threadIdx.x) * 4;
  float4 v = *(const float4*)(s + i);
  ushort4 o;
  o.x = f2bf(v.x); o.y = f2bf(v.y); o.z = f2bf(v.z); o.w = f2bf(v.w);
  *(ushort4*)(d + i) = o;
}

__device__ __forceinline__ void stage16(const void* g, void* l) {
  __builtin_amdgcn_global_load_lds(
      (const __attribute__((address_space(1))) void*)g,
      (__attribute__((address_space(3))) void*)l, 16, 0, 0);
}

// 128x128-tile GEMM: C = A[4096xK]*Bm[1024xK]^T + bias, scaled.
// mode 0: fp32 [4096][1024]; mode 1: bf16 [B,H,S,D]; mode 2: bf16 [B,H,D,S]
__device__ __forceinline__ void gemm128(const unsigned short* __restrict__ A,
                                        const unsigned short* __restrict__ Bm,
                                        const float* __restrict__ bias, float scale,
                                        void* __restrict__ outp, int mode,
                                        unsigned short* As, unsigned short* Bs) {
  const int tid  = threadIdx.x;
  const int lane = tid & 63;
  const int wave = tid >> 6;
  const int m16  = lane & 15;
  const int quad = lane >> 4;
  const int m0 = blockIdx.x * BM;
  const int n0 = blockIdx.y * BN;
  const int wrow = (wave >> 1) * 64;
  const int wcol = (wave & 1) * 64;
  const int K = 1024, N = 1024;

  floatx4 acc[4][4];
  for (int i = 0; i < 4; ++i)
    for (int j = 0; j < 4; ++j) acc[i][j] = floatx4{0.f, 0.f, 0.f, 0.f};

  for (int k0 = 0; k0 < K; k0 += BK) {
    __syncthreads();
    for (int i = 0; i < 4; ++i) {
      int c   = i * 256 + tid;
      int row = c >> 3;
      int col = (c & 7) << 3;
      stage16(A  + (size_t)(m0 + row) * K + k0 + col,
              (char*)As + (size_t)(i * 256 + wave * 64) * 16);
      stage16(Bm + (size_t)(n0 + row) * K + k0 + col,
              (char*)Bs + (size_t)(i * 256 + wave * 64) * 16);
    }
    __syncthreads();
    for (int kk = 0; kk < 2; ++kk) {
      bf16x8 af[4], bfr[4];
      for (int ti = 0; ti < 4; ++ti)
        af[ti] = *(const bf16x8*)(As + (wrow + ti * 16 + m16) * BK + kk * 32 + quad * 8);
      for (int tj = 0; tj < 4; ++tj)
        bfr[tj] = *(const bf16x8*)(Bs + (wcol + tj * 16 + m16) * BK + kk * 32 + quad * 8);
      for (int ti = 0; ti < 4; ++ti)
        for (int tj = 0; tj < 4; ++tj)
          acc[ti][tj] = __builtin_amdgcn_mfma_f32_16x16x32_bf16(af[ti], bfr[tj], acc[ti][tj], 0, 0, 0);
    }
  }

  for (int tj = 0; tj < 4; ++tj) {
    int n = n0 + wcol + tj * 16 + m16;
    float bv = bias[n];
    for (int ti = 0; ti < 4; ++ti) {
      for (int reg = 0; reg < 4; ++reg) {
        int m = m0 + wrow + ti * 16 + quad * 4 + reg;
        float v = (acc[ti][tj][reg] + bv) * scale;
        if (mode == 0) {
          ((float*)outp)[(size_t)m * N + n] = v;
        } else {
          int b = m >> 11, s = m & 2047, hh = n >> 6, d = n & 63;
          unsigned short bb = f2bf(v);
          if (mode == 1)
            ((unsigned short*)outp)[((size_t)(b * NH + hh) * S_LEN + s) * HD + d] = bb;
          else
            ((unsigned short*)outp)[((size_t)(b * NH + hh) * HD + d) * S_LEN + s] = bb;
        }
      }
    }
  }
}

__global__ __launch_bounds__(256) void qkv_gemm(const unsigned short* __restrict__ xb,
                                                const unsigned short* __restrict__ Wqb,
                                                const unsigned short* __restrict__ Wkb,
                                                const unsigned short* __restrict__ Wvb,
                                                const float* __restrict__ bq,
                                                const float* __restrict__ bk,
                                                const float* __restrict__ bv,
                                                unsigned short* __restrict__ Qb,
                                                unsigned short* __restrict__ Kb,
                                                unsigned short* __restrict__ Vtb) {
  __shared__ unsigned short As[BM * BK];
  __shared__ unsigned short Bs[BN * BK];
  int z = blockIdx.z;
  const unsigned short* Bm = (z == 0) ? Wqb : (z == 1) ? Wkb : Wvb;
  const float* bias        = (z == 0) ? bq  : (z == 1) ? bk  : bv;
  unsigned short* outp     = (z == 0) ? Qb  : (z == 1) ? Kb  : Vtb;
  float scale = (z == 0) ? QSCALE : 1.0f;
  gemm128(xb, Bm, bias, scale, outp, (z == 2) ? 2 : 1, As, Bs);
}

// 64x128-tile GEMM for the output projection: grid 64x8 = 512 blocks -> 2/CU.
__global__ __launch_bounds__(256) void out_gemm(const unsigned short* __restrict__ Ab,
                                                const unsigned short* __restrict__ Wob,
                                                const float* __restrict__ bo,
                                                float* __restrict__ out) {
  __shared__ unsigned short As[64 * BK];
  __shared__ unsigned short Bs[128 * BK];
  const int tid  = threadIdx.x;
  const int lane = tid & 63;
  const int wave = tid >> 6;
  const int m16  = lane & 15;
  const int quad = lane >> 4;
  const int m0 = blockIdx.x * 64;
  const int n0 = blockIdx.y * 128;
  const int wrow = (wave >> 1) * 32;
  const int wcol = (wave & 1) * 64;
  const int K = 1024, N = 1024;

  floatx4 acc[2][4];
  for (int i = 0; i < 2; ++i)
    for (int j = 0; j < 4; ++j) acc[i][j] = floatx4{0.f, 0.f, 0.f, 0.f};

  for (int k0 = 0; k0 < K; k0 += BK) {
    __syncthreads();
    for (int i = 0; i < 2; ++i) {
      int c = i * 256 + tid;
      int row = c >> 3, col = (c & 7) << 3;
      stage16(Ab + (size_t)(m0 + row) * K + k0 + col,
              (char*)As + (size_t)(i * 256 + wave * 64) * 16);
    }
    for (int i = 0; i < 4; ++i) {
      int c = i * 256 + tid;
      int row = c >> 3, col = (c & 7) << 3;
      stage16(Wob + (size_t)(n0 + row) * K + k0 + col,
              (char*)Bs + (size_t)(i * 256 + wave * 64) * 16);
    }
    __syncthreads();
    for (int kk = 0; kk < 2; ++kk) {
      bf16x8 af[2], bfr[4];
      for (int ti = 0; ti < 2; ++ti)
        af[ti] = *(const bf16x8*)(As + (wrow + ti * 16 + m16) * BK + kk * 32 + quad * 8);
      for (int tj = 0; tj < 4; ++tj)
        bfr[tj] = *(const bf16x8*)(Bs + (wcol + tj * 16 + m16) * BK + kk * 32 + quad * 8);
      for (int ti = 0; ti < 2; ++ti)
        for (int tj = 0; tj < 4; ++tj)
          acc[ti][tj] = __builtin_amdgcn_mfma_f32_16x16x32_bf16(af[ti], bfr[tj], acc[ti][tj], 0, 0, 0);
    }
  }

  for (int tj = 0; tj < 4; ++tj) {
    int n = n0 + wcol + tj * 16 + m16;
    float bv = bo[n];
    for (int ti = 0; ti < 2; ++ti)
      for (int reg = 0; reg < 4; ++reg) {
        int m = m0 + wrow + ti * 16 + quad * 4 + reg;
        out[(size_t)m * N + n] = acc[ti][tj][reg] + bv;
      }
  }
}

// Flash attention v3: 512 threads, 128 q-rows/block (8 waves x 16q), 64-kv tiles.
// S^T = K Q^T (softmax in-register); exp2 domain (scale folded into Q);
// P packed via v_perm round-half-up; K/V global loads register-double-buffered.
__global__ __launch_bounds__(512, 2) void attn_kernel(const unsigned short* __restrict__ Qb,  // [B,H,S,D] *QSCALE
                                                      const unsigned short* __restrict__ Kb,  // [B,H,S,D]
                                                      const unsigned short* __restrict__ Vtb, // [B,H,D,S]
                                                      const int* __restrict__ mask,           // [B,S]
                                                      unsigned short* __restrict__ attnb) {   // [B,S,E]
  __shared__ unsigned short Ks[64 * 72];   // [kv][d]
  __shared__ unsigned short Vts[64 * 72];  // [d][kv]
  __shared__ float mb[64];
#ifndef HAVE_MFMA16
  __shared__ unsigned short Pq[8 * 16 * 72];
#endif

  const int tid  = threadIdx.x;
  const int lane = tid & 63;
  const int wave = tid >> 6;          // 0..7
  const int m16  = lane & 15;
  const int quad = lane >> 4;
  const int qt = blockIdx.x;          // 0..15
  const int bh = blockIdx.y;          // 0..31
  const int b  = bh >> 4;
  const int h  = bh & 15;
  const int q0 = qt * 128;
  const size_t head = (size_t)bh * S_LEN * HD;

  bf16x8 qf[2];
  {
    const unsigned short* qrow = Qb + head + (size_t)(q0 + wave * 16 + m16) * HD;
    qf[0] = *(const bf16x8*)(qrow + quad * 8);
    qf[1] = *(const bf16x8*)(qrow + 32 + quad * 8);
  }

  const int srow = tid >> 3;              // staging: 1 K-chunk + 1 V-chunk per thread
  const int sdch = (tid & 7) << 3;
  const unsigned short* kbase = Kb  + head + (size_t)srow * HD + sdch;
  const unsigned short* vbase = Vtb + head + (size_t)srow * S_LEN + sdch;

  float m_run = -1e30f, l_run = 0.f;
  floatx4 acc_o[4];
  for (int ti = 0; ti < 4; ++ti) acc_o[ti] = floatx4{0.f, 0.f, 0.f, 0.f};

  // prefetch tile 0
  uint4 kv_pre = *(const uint4*)(kbase);
  uint4 vv_pre = *(const uint4*)(vbase);
  int   mk_pre = (tid < 64) ? mask[b * S_LEN + tid] : 1;

  for (int kb = 0; kb < 32; ++kb) {
    __syncthreads();  // prior compute's LDS reads done
    *(uint4*)&Ks[srow * 72 + sdch]  = kv_pre;
    *(uint4*)&Vts[srow * 72 + sdch] = vv_pre;
    if (tid < 64) mb[tid] = (mk_pre == 0) ? -1e9f : 0.f;
    __syncthreads();

    // prefetch next tile (issue loads during compute phase)
    {
      int kvn = (kb + 1 < 32) ? (kb + 1) * 64 : 0;
      kv_pre = *(const uint4*)(kbase + (size_t)kvn * HD);
      vv_pre = *(const uint4*)(vbase + kvn);
      if (tid < 64) mk_pre = mask[b * S_LEN + kvn + tid];
    }

    // S^T[kv][q]: A = K fragment (m=kv), B = Q fragment (n=q)
    floatx4 acc_s[4];
    for (int tj = 0; tj < 4; ++tj) acc_s[tj] = floatx4{0.f, 0.f, 0.f, 0.f};
    for (int kk = 0; kk < 2; ++kk)
      for (int tj = 0; tj < 4; ++tj) {
        bf16x8 kf = *(const bf16x8*)&Ks[(tj * 16 + m16) * 72 + kk * 32 + quad * 8];
        acc_s[tj] = __builtin_amdgcn_mfma_f32_16x16x32_bf16(kf, qf[kk], acc_s[tj], 0, 0, 0);
      }

    float s[16];
    for (int t = 0; t < 4; ++t) {
      float4 mv = *(const float4*)&mb[t * 16 + quad * 4];
      s[t * 4 + 0] = acc_s[t][0] + mv.x;
      s[t * 4 + 1] = acc_s[t][1] + mv.y;
      s[t * 4 + 2] = acc_s[t][2] + mv.z;
      s[t * 4 + 3] = acc_s[t][3] + mv.w;
    }
    float mloc = fmaxf(fmaxf(fmaxf(s[0], s[1]), fmaxf(s[2], s[3])),
                       fmaxf(fmaxf(s[4], s[5]), fmaxf(s[6], s[7])));
    float mloc2 = fmaxf(fmaxf(fmaxf(s[8], s[9]), fmaxf(s[10], s[11])),
                        fmaxf(fmaxf(s[12], s[13]), fmaxf(s[14], s[15])));
    mloc = fmaxf(mloc, mloc2);
    mloc = fmaxf(mloc, __shfl_xor(mloc, 16));
    mloc = fmaxf(mloc, __shfl_xor(mloc, 32));
    float mnew = fmaxf(m_run, mloc);
    float alpha = EXP2F(m_run - mnew);
    m_run = mnew;

    unsigned up[8];
    float sl = 0.f;
    for (int i = 0; i < 8; ++i) {
      float p0 = EXP2F(s[2 * i] - mnew);
      float p1 = EXP2F(s[2 * i + 1] - mnew);
      unsigned u0 = __builtin_bit_cast(unsigned, p0) + 0x8000u;  // round-half-up to bf16
      unsigned u1 = __builtin_bit_cast(unsigned, p1) + 0x8000u;
      up[i] = __builtin_amdgcn_perm(u1, u0, 0x07060302);         // [bf16(p1):bf16(p0)]
      sl += __builtin_bit_cast(float, u0 & 0xffff0000u) +
            __builtin_bit_cast(float, u1 & 0xffff0000u);         // sum what we store
    }
    sl += __shfl_xor(sl, 16);
    sl += __shfl_xor(sl, 32);
    l_run = l_run * alpha + sl;

    for (int ti = 0; ti < 4; ++ti)
      for (int reg = 0; reg < 4; ++reg) acc_o[ti][reg] *= alpha;

#ifdef HAVE_MFMA16
    for (int ti = 0; ti < 4; ++ti)
      for (int c = 0; c < 4; ++c) {
        short4v vf = *(const short4v*)&Vts[(ti * 16 + m16) * 72 + c * 16 + quad * 4];
        short4v Pb = __builtin_bit_cast(short4v, uint2v{up[2 * c], up[2 * c + 1]});
        acc_o[ti] = __builtin_amdgcn_mfma_f32_16x16x16bf16_1k(vf, Pb, acc_o[ti], 0, 0, 0);
      }
#else
    unsigned short* Pw = Pq + wave * 16 * 72;
    for (int t = 0; t < 4; ++t) {
      *(unsigned*)&Pw[m16 * 72 + t * 16 + quad * 4]     = up[2 * t];
      *(unsigned*)&Pw[m16 * 72 + t * 16 + quad * 4 + 2] = up[2 * t + 1];
    }
    for (int kk = 0; kk < 2; ++kk) {
      bf16x8 pf = *(const bf16x8*)&Pw[m16 * 72 + kk * 32 + quad * 8];
      for (int ti = 0; ti < 4; ++ti) {
        bf16x8 vf = *(const bf16x8*)&Vts[(ti * 16 + m16) * 72 + kk * 32 + quad * 8];
        acc_o[ti] = __builtin_amdgcn_mfma_f32_16x16x32_bf16(vf, pf, acc_o[ti], 0, 0, 0);
      }
    }
#endif
  }

  float rl = 1.f / l_run;
  int orow = q0 + wave * 16 + m16;
  for (int ti = 0; ti < 4; ++ti) {
    ushort4 o;
    o.x = f2bf(acc_o[ti][0] * rl);
    o.y = f2bf(acc_o[ti][1] * rl);
    o.z = f2bf(acc_o[ti][2] * rl);
    o.w = f2bf(acc_o[ti][3] * rl);
    int e = h * HD + ti * 16 + quad * 4;
    *(ushort4*)&attnb[((size_t)(b * S_LEN + orow)) * EMB + e] = o;
  }
}

extern "C" void kernel_launch(void* const* d_in, const int* in_sizes, int n_in,
                              void* d_out, int out_size, void* d_ws, size_t ws_size,
                              hipStream_t stream) {
  const float* x  = (const float*)d_in[0];
  const int* mask = (const int*)d_in[1];
  const float* Wq = (const float*)d_in[2];
  const float* bq = (const float*)d_in[3];
  const float* Wk = (const float*)d_in[4];
  const float* bk = (const float*)d_in[5];
  const float* Wv = (const float*)d_in[6];
  const float* bv = (const float*)d_in[7];
  const float* Wo = (const float*)d_in[8];
  const float* bo = (const float*)d_in[9];
  float* out = (float*)d_out;

  char* ws = (char*)d_ws;
  unsigned short* xb  = (unsigned short*)(ws);               // 8 MB
  unsigned short* Wqb = (unsigned short*)(ws + 8388608);     // 2 MB
  unsigned short* Wkb = (unsigned short*)(ws + 10485760);    // 2 MB
  unsigned short* Wvb = (unsigned short*)(ws + 12582912);    // 2 MB
  unsigned short* Wob = (unsigned short*)(ws + 14680064);    // 2 MB
  unsigned short* Qb  = (unsigned short*)(ws + 16777216);    // 8 MB [B,H,S,D]
  unsigned short* Kbb = (unsigned short*)(ws + 25165824);    // 8 MB [B,H,S,D]
  unsigned short* Vtb = (unsigned short*)(ws + 33554432);    // 8 MB [B,H,D,S]
  unsigned short* Ab  = (unsigned short*)(ws + 41943040);    // 8 MB [B,S,E]

  cvt_all<<<dim3(8192), dim3(256), 0, stream>>>(x, Wq, Wk, Wv, Wo, xb, Wqb, Wkb, Wvb, Wob);
  qkv_gemm<<<dim3(32, 8, 3), dim3(256), 0, stream>>>(xb, Wqb, Wkb, Wvb, bq, bk, bv, Qb, Kbb, Vtb);
  attn_kernel<<<dim3(16, 32), dim3(512), 0, stream>>>(Qb, Kbb, Vtb, mask, Ab);
  out_gemm<<<dim3(64, 8), dim3(256), 0, stream>>>(Ab, Wob, bo, out);
}

// Round 4
// 228.811 us; speedup vs baseline: 1.4806x; 1.0793x over previous
//
#include <hip/hip_runtime.h>
#include <stdint.h>

#define S_LEN 2048
#define EMB   1024
#define NH    16
#define HD    64
#define BM 128
#define BN 128
#define BK 64

typedef __bf16 bf16x8 __attribute__((ext_vector_type(8)));
typedef short  short4v __attribute__((ext_vector_type(4)));
typedef unsigned int uint2v __attribute__((ext_vector_type(2)));
typedef float  floatx4 __attribute__((ext_vector_type(4)));

#if defined(__has_builtin)
#if __has_builtin(__builtin_amdgcn_mfma_f32_16x16x16bf16_1k)
#define HAVE_MFMA16 1
#endif
#if __has_builtin(__builtin_amdgcn_exp2f)
#define EXP2F(x) __builtin_amdgcn_exp2f(x)
#endif
#endif
#ifndef EXP2F
#define EXP2F(x) exp2f(x)
#endif

// 0.125 (1/sqrt(64)) * log2(e): Q pre-scale so softmax runs in exp2 domain
#define QSCALE 0.1803368801111204f

__device__ __forceinline__ unsigned short f2bf(float f) {
  unsigned u = __builtin_bit_cast(unsigned, f);
  u += 0x7fffu + ((u >> 16) & 1u);   // RNE
  return (unsigned short)(u >> 16);
}

__global__ __launch_bounds__(256) void cvt_all(const float* __restrict__ x,
                                               const float* __restrict__ Wq,
                                               const float* __restrict__ Wk,
                                               const float* __restrict__ Wv,
                                               const float* __restrict__ Wo,
                                               unsigned short* __restrict__ xb,
                                               unsigned short* __restrict__ Wqb,
                                               unsigned short* __restrict__ Wkb,
                                               unsigned short* __restrict__ Wvb,
                                               unsigned short* __restrict__ Wob) {
  int blk = blockIdx.x;
  const float* s; unsigned short* d; int off;
  if (blk < 4096)      { s = x;  d = xb;  off = blk; }
  else if (blk < 5120) { s = Wq; d = Wqb; off = blk - 4096; }
  else if (blk < 6144) { s = Wk; d = Wkb; off = blk - 5120; }
  else if (blk < 7168) { s = Wv; d = Wvb; off = blk - 6144; }
  else                 { s = Wo; d = Wob; off = blk - 7168; }
  int i = (off * 256 + threadIdx.x) * 4;
  float4 v = *(const float4*)(s + i);
  ushort4 o;
  o.x = f2bf(v.x); o.y = f2bf(v.y); o.z = f2bf(v.z); o.w = f2bf(v.w);
  *(ushort4*)(d + i) = o;
}

__device__ __forceinline__ void stage16(const void* g, void* l) {
  __builtin_amdgcn_global_load_lds(
      (const __attribute__((address_space(1))) void*)g,
      (__attribute__((address_space(3))) void*)l, 16, 0, 0);
}

// 128x128-tile GEMM: C = A[4096xK]*Bm[1024xK]^T + bias, scaled.
// mode 0: fp32 [4096][1024]; mode 1: bf16 [B,H,S,D]
// mode 2: bf16 [B,H,D,S] via operand swap (C' = Bm * A^T) so stores coalesce along s
__device__ __forceinline__ void gemm128(const unsigned short* __restrict__ A,
                                        const unsigned short* __restrict__ Bm,
                                        const float* __restrict__ bias, float scale,
                                        void* __restrict__ outp, int mode,
                                        unsigned short* As, unsigned short* Bs) {
  const int tid  = threadIdx.x;
  const int lane = tid & 63;
  const int wave = tid >> 6;
  const int m16  = lane & 15;
  const int quad = lane >> 4;
  const int m0 = blockIdx.x * BM;
  const int n0 = blockIdx.y * BN;
  const int wrow = (wave >> 1) * 64;
  const int wcol = (wave & 1) * 64;
  const int K = 1024, N = 1024;

  floatx4 acc[4][4];
  for (int i = 0; i < 4; ++i)
    for (int j = 0; j < 4; ++j) acc[i][j] = floatx4{0.f, 0.f, 0.f, 0.f};

  for (int k0 = 0; k0 < K; k0 += BK) {
    __syncthreads();
    for (int i = 0; i < 4; ++i) {
      int c   = i * 256 + tid;
      int row = c >> 3;
      int col = (c & 7) << 3;
      stage16(A  + (size_t)(m0 + row) * K + k0 + col,
              (char*)As + (size_t)(i * 256 + wave * 64) * 16);
      stage16(Bm + (size_t)(n0 + row) * K + k0 + col,
              (char*)Bs + (size_t)(i * 256 + wave * 64) * 16);
    }
    __syncthreads();
    for (int kk = 0; kk < 2; ++kk) {
      bf16x8 af[4], bfr[4];
      for (int ti = 0; ti < 4; ++ti)
        af[ti] = *(const bf16x8*)(As + (wrow + ti * 16 + m16) * BK + kk * 32 + quad * 8);
      for (int tj = 0; tj < 4; ++tj)
        bfr[tj] = *(const bf16x8*)(Bs + (wcol + tj * 16 + m16) * BK + kk * 32 + quad * 8);
      if (mode == 2) {
        for (int ti = 0; ti < 4; ++ti)
          for (int tj = 0; tj < 4; ++tj)
            acc[ti][tj] = __builtin_amdgcn_mfma_f32_16x16x32_bf16(bfr[tj], af[ti], acc[ti][tj], 0, 0, 0);
      } else {
        for (int ti = 0; ti < 4; ++ti)
          for (int tj = 0; tj < 4; ++tj)
            acc[ti][tj] = __builtin_amdgcn_mfma_f32_16x16x32_bf16(af[ti], bfr[tj], acc[ti][tj], 0, 0, 0);
      }
    }
  }

  if (mode == 2) {
    // C' rows = Bm-rows (d'), cols = A-rows (s): coalesced along s
    for (int tj = 0; tj < 4; ++tj) {
      for (int reg = 0; reg < 4; ++reg) {
        int n = n0 + wcol + tj * 16 + quad * 4 + reg;   // W-row = output feature
        int hh = n >> 6, d = n & 63;
        float bv = bias[n];
        for (int ti = 0; ti < 4; ++ti) {
          int m = m0 + wrow + ti * 16 + m16;            // x-row = (b,s)
          int b = m >> 11, s = m & 2047;
          ((unsigned short*)outp)[((size_t)(b * NH + hh) * HD + d) * S_LEN + s] =
              f2bf(acc[ti][tj][reg] + bv);
        }
      }
    }
    return;
  }

  for (int tj = 0; tj < 4; ++tj) {
    int n = n0 + wcol + tj * 16 + m16;
    float bv = bias[n];
    for (int ti = 0; ti < 4; ++ti) {
      for (int reg = 0; reg < 4; ++reg) {
        int m = m0 + wrow + ti * 16 + quad * 4 + reg;
        float v = (acc[ti][tj][reg] + bv) * scale;
        if (mode == 0) {
          ((float*)outp)[(size_t)m * N + n] = v;
        } else {
          int b = m >> 11, s = m & 2047, hh = n >> 6, d = n & 63;
          ((unsigned short*)outp)[((size_t)(b * NH + hh) * S_LEN + s) * HD + d] = f2bf(v);
        }
      }
    }
  }
}

__global__ __launch_bounds__(256) void qkv_gemm(const unsigned short* __restrict__ xb,
                                                const unsigned short* __restrict__ Wqb,
                                                const unsigned short* __restrict__ Wkb,
                                                const unsigned short* __restrict__ Wvb,
                                                const float* __restrict__ bq,
                                                const float* __restrict__ bk,
                                                const float* __restrict__ bv,
                                                unsigned short* __restrict__ Qb,
                                                unsigned short* __restrict__ Kb,
                                                unsigned short* __restrict__ Vtb) {
  __shared__ unsigned short As[BM * BK];
  __shared__ unsigned short Bs[BN * BK];
  int z = blockIdx.z;
  const unsigned short* Bm = (z == 0) ? Wqb : (z == 1) ? Wkb : Wvb;
  const float* bias        = (z == 0) ? bq  : (z == 1) ? bk  : bv;
  unsigned short* outp     = (z == 0) ? Qb  : (z == 1) ? Kb  : Vtb;
  float scale = (z == 0) ? QSCALE : 1.0f;
  gemm128(xb, Bm, bias, scale, outp, (z == 2) ? 2 : 1, As, Bs);
}

// 64x128-tile GEMM for the output projection: 512 blocks -> 2/CU.
__global__ __launch_bounds__(256) void out_gemm(const unsigned short* __restrict__ Ab,
                                                const unsigned short* __restrict__ Wob,
                                                const float* __restrict__ bo,
                                                float* __restrict__ out) {
  __shared__ unsigned short As[64 * BK];
  __shared__ unsigned short Bs[128 * BK];
  const int tid  = threadIdx.x;
  const int lane = tid & 63;
  const int wave = tid >> 6;
  const int m16  = lane & 15;
  const int quad = lane >> 4;
  const int m0 = blockIdx.x * 64;
  const int n0 = blockIdx.y * 128;
  const int wrow = (wave >> 1) * 32;
  const int wcol = (wave & 1) * 64;
  const int K = 1024, N = 1024;

  floatx4 acc[2][4];
  for (int i = 0; i < 2; ++i)
    for (int j = 0; j < 4; ++j) acc[i][j] = floatx4{0.f, 0.f, 0.f, 0.f};

  for (int k0 = 0; k0 < K; k0 += BK) {
    __syncthreads();
    for (int i = 0; i < 2; ++i) {
      int c = i * 256 + tid;
      int row = c >> 3, col = (c & 7) << 3;
      stage16(Ab + (size_t)(m0 + row) * K + k0 + col,
              (char*)As + (size_t)(i * 256 + wave * 64) * 16);
    }
    for (int i = 0; i < 4; ++i) {
      int c = i * 256 + tid;
      int row = c >> 3, col = (c & 7) << 3;
      stage16(Wob + (size_t)(n0 + row) * K + k0 + col,
              (char*)Bs + (size_t)(i * 256 + wave * 64) * 16);
    }
    __syncthreads();
    for (int kk = 0; kk < 2; ++kk) {
      bf16x8 af[2], bfr[4];
      for (int ti = 0; ti < 2; ++ti)
        af[ti] = *(const bf16x8*)(As + (wrow + ti * 16 + m16) * BK + kk * 32 + quad * 8);
      for (int tj = 0; tj < 4; ++tj)
        bfr[tj] = *(const bf16x8*)(Bs + (wcol + tj * 16 + m16) * BK + kk * 32 + quad * 8);
      for (int ti = 0; ti < 2; ++ti)
        for (int tj = 0; tj < 4; ++tj)
          acc[ti][tj] = __builtin_amdgcn_mfma_f32_16x16x32_bf16(af[ti], bfr[tj], acc[ti][tj], 0, 0, 0);
    }
  }

  for (int tj = 0; tj < 4; ++tj) {
    int n = n0 + wcol + tj * 16 + m16;
    float bv = bo[n];
    for (int ti = 0; ti < 2; ++ti)
      for (int reg = 0; reg < 4; ++reg) {
        int m = m0 + wrow + ti * 16 + quad * 4 + reg;
        out[(size_t)m * N + n] = acc[ti][tj][reg] + bv;
      }
  }
}

// Flash attention v4: 512 thr, 128 q-rows/block, 128-kv tiles (2x 64-kv halves).
// XOR-swizzled LDS (conflict-free), XCD-pinned grid (bh = blockIdx.x -> XCD=bh%8),
// wave-uniform skip of alpha-rescale, register-double-buffered K/V staging.
__global__ __launch_bounds__(512, 2) void attn_kernel(const unsigned short* __restrict__ Qb,  // [B,H,S,D] *QSCALE
                                                      const unsigned short* __restrict__ Kb,  // [B,H,S,D]
                                                      const unsigned short* __restrict__ Vtb, // [B,H,D,S]
                                                      const int* __restrict__ mask,           // [B,S]
                                                      unsigned short* __restrict__ attnb) {   // [B,S,E]
  __shared__ unsigned short Ks[128 * 64];   // [kv][d], chunk' = chunk ^ (kv&7)
  __shared__ unsigned short Vts[64 * 128];  // [d][kv], chunk' = chunk ^ (d&7)
  __shared__ float mb[128];
#ifndef HAVE_MFMA16
  __shared__ unsigned short Pq[8 * 16 * 72];
#endif

  const int tid  = threadIdx.x;
  const int lane = tid & 63;
  const int wave = tid >> 6;          // 0..7
  const int m16  = lane & 15;
  const int quad = lane >> 4;
  const int bh = blockIdx.x;          // 0..31  (fastest -> XCD = bh % 8)
  const int qt = blockIdx.y;          // 0..15
  const int b  = bh >> 4;
  const int h  = bh & 15;
  const int q0 = qt * 128;
  const size_t head = (size_t)bh * S_LEN * HD;

  bf16x8 qf[2];
  {
    const unsigned short* qrow = Qb + head + (size_t)(q0 + wave * 16 + m16) * HD;
    qf[0] = *(const bf16x8*)(qrow + quad * 8);
    qf[1] = *(const bf16x8*)(qrow + 32 + quad * 8);
  }

  // staging addresses (swizzled LDS dest, fixed per thread)
  const int krow = tid >> 3, kch = tid & 7;
  const unsigned short* kg = Kb + head + (size_t)krow * HD + kch * 8;
  unsigned short* kl = Ks + krow * 64 + (kch ^ (krow & 7)) * 8;
  const int vrow = tid >> 4, vch = tid & 15;
  const unsigned short* vg = Vtb + head + (size_t)vrow * S_LEN + vch * 8;
  unsigned short* vl = Vts + vrow * 128 + (vch ^ (vrow & 7)) * 8;

  float m_run = -1e30f, l_run = 0.f;
  floatx4 acc_o[4];
  for (int ti = 0; ti < 4; ++ti) acc_o[ti] = floatx4{0.f, 0.f, 0.f, 0.f};

  // prefetch tile 0 (128 kv)
  uint4 kp0 = *(const uint4*)(kg);
  uint4 kp1 = *(const uint4*)(kg + 64 * HD);
  uint4 vp0 = *(const uint4*)(vg);
  uint4 vp1 = *(const uint4*)(vg + 32 * S_LEN);
  int   mp  = (tid < 128) ? mask[b * S_LEN + tid] : 1;

  const int xs = m16 & 7;   // XOR swizzle key for this lane's rows

  for (int kb = 0; kb < 16; ++kb) {
    __syncthreads();
    *(uint4*)kl = kp0;  *(uint4*)(kl + 64 * 64) = kp1;
    *(uint4*)vl = vp0;  *(uint4*)(vl + 32 * 128) = vp1;
    if (tid < 128) mb[tid] = (mp == 0) ? -1e9f : 0.f;
    __syncthreads();

    {
      int kvn = (kb + 1 < 16) ? (kb + 1) * 128 : 0;
      kp0 = *(const uint4*)(kg + (size_t)kvn * HD);
      kp1 = *(const uint4*)(kg + (size_t)(kvn + 64) * HD);
      vp0 = *(const uint4*)(vg + kvn);
      vp1 = *(const uint4*)(vg + 32 * S_LEN + kvn);
      if (tid < 128) mp = mask[b * S_LEN + kvn + tid];
    }

    for (int hf = 0; hf < 2; ++hf) {
      // S^T[kv][q]: A = K fragment (m = kv), B = Q fragment (n = q)
      floatx4 acc_s[4];
      for (int tj = 0; tj < 4; ++tj) acc_s[tj] = floatx4{0.f, 0.f, 0.f, 0.f};
      for (int kk = 0; kk < 2; ++kk)
        for (int tj = 0; tj < 4; ++tj) {
          bf16x8 kf = *(const bf16x8*)&Ks[(hf * 64 + tj * 16 + m16) * 64 +
                                          (((kk * 4 + quad) ^ xs) << 3)];
          acc_s[tj] = __builtin_amdgcn_mfma_f32_16x16x32_bf16(kf, qf[kk], acc_s[tj], 0, 0, 0);
        }

      float s[16];
      for (int t = 0; t < 4; ++t) {
        float4 mv = *(const float4*)&mb[hf * 64 + t * 16 + quad * 4];
        s[t * 4 + 0] = acc_s[t][0] + mv.x;
        s[t * 4 + 1] = acc_s[t][1] + mv.y;
        s[t * 4 + 2] = acc_s[t][2] + mv.z;
        s[t * 4 + 3] = acc_s[t][3] + mv.w;
      }
      float mloc = fmaxf(fmaxf(fmaxf(s[0], s[1]), fmaxf(s[2], s[3])),
                         fmaxf(fmaxf(s[4], s[5]), fmaxf(s[6], s[7])));
      float mloc2 = fmaxf(fmaxf(fmaxf(s[8], s[9]), fmaxf(s[10], s[11])),
                          fmaxf(fmaxf(s[12], s[13]), fmaxf(s[14], s[15])));
      mloc = fmaxf(mloc, mloc2);
      mloc = fmaxf(mloc, __shfl_xor(mloc, 16));
      mloc = fmaxf(mloc, __shfl_xor(mloc, 32));

      if (__any(mloc > m_run)) {          // wave-uniform; ~11% of iterations
        float mnew = fmaxf(m_run, mloc);
        float alpha = EXP2F(m_run - mnew);
        m_run = mnew;
        l_run *= alpha;
        for (int ti = 0; ti < 4; ++ti)
          for (int reg = 0; reg < 4; ++reg) acc_o[ti][reg] *= alpha;
      }

      unsigned up[8];
      float sl = 0.f;
      for (int i = 0; i < 8; ++i) {
        float p0 = EXP2F(s[2 * i] - m_run);
        float p1 = EXP2F(s[2 * i + 1] - m_run);
        unsigned u0 = __builtin_bit_cast(unsigned, p0) + 0x8000u;  // round-half-up to bf16
        unsigned u1 = __builtin_bit_cast(unsigned, p1) + 0x8000u;
        up[i] = __builtin_amdgcn_perm(u1, u0, 0x07060302);
        sl += __builtin_bit_cast(float, u0 & 0xffff0000u) +
              __builtin_bit_cast(float, u1 & 0xffff0000u);
      }
      sl += __shfl_xor(sl, 16);
      sl += __shfl_xor(sl, 32);
      l_run += sl;

#ifdef HAVE_MFMA16
      for (int ti = 0; ti < 4; ++ti)
        for (int c = 0; c < 4; ++c) {
          short4v vf = *(const short4v*)&Vts[(ti * 16 + m16) * 128 +
                                             (((hf * 8 + 2 * c + (quad >> 1)) ^ xs) << 3) +
                                             ((quad & 1) << 2)];
          short4v Pb = __builtin_bit_cast(short4v, uint2v{up[2 * c], up[2 * c + 1]});
          acc_o[ti] = __builtin_amdgcn_mfma_f32_16x16x16bf16_1k(vf, Pb, acc_o[ti], 0, 0, 0);
        }
#else
      unsigned short* Pw = Pq + wave * 16 * 72;
      for (int t = 0; t < 4; ++t) {
        *(unsigned*)&Pw[m16 * 72 + t * 16 + quad * 4]     = up[2 * t];
        *(unsigned*)&Pw[m16 * 72 + t * 16 + quad * 4 + 2] = up[2 * t + 1];
      }
      for (int kk = 0; kk < 2; ++kk) {
        bf16x8 pf = *(const bf16x8*)&Pw[m16 * 72 + kk * 32 + quad * 8];
        for (int ti = 0; ti < 4; ++ti) {
          bf16x8 vf = *(const bf16x8*)&Vts[(ti * 16 + m16) * 128 +
                                           (((hf * 8 + kk * 4 + quad) ^ xs) << 3)];
          acc_o[ti] = __builtin_amdgcn_mfma_f32_16x16x32_bf16(vf, pf, acc_o[ti], 0, 0, 0);
        }
      }
#endif
    }
  }

  float rl = 1.f / l_run;
  int orow = q0 + wave * 16 + m16;
  for (int ti = 0; ti < 4; ++ti) {
    ushort4 o;
    o.x = f2bf(acc_o[ti][0] * rl);
    o.y = f2bf(acc_o[ti][1] * rl);
    o.z = f2bf(acc_o[ti][2] * rl);
    o.w = f2bf(acc_o[ti][3] * rl);
    int e = h * HD + ti * 16 + quad * 4;
    *(ushort4*)&attnb[((size_t)(b * S_LEN + orow)) * EMB + e] = o;
  }
}

extern "C" void kernel_launch(void* const* d_in, const int* in_sizes, int n_in,
                              void* d_out, int out_size, void* d_ws, size_t ws_size,
                              hipStream_t stream) {
  const float* x  = (const float*)d_in[0];
  const int* mask = (const int*)d_in[1];
  const float* Wq = (const float*)d_in[2];
  const float* bq = (const float*)d_in[3];
  const float* Wk = (const float*)d_in[4];
  const float* bk = (const float*)d_in[5];
  const float* Wv = (const float*)d_in[6];
  const float* bv = (const float*)d_in[7];
  const float* Wo = (const float*)d_in[8];
  const float* bo = (const float*)d_in[9];
  float* out = (float*)d_out;

  char* ws = (char*)d_ws;
  unsigned short* xb  = (unsigned short*)(ws);               // 8 MB
  unsigned short* Wqb = (unsigned short*)(ws + 8388608);     // 2 MB
  unsigned short* Wkb = (unsigned short*)(ws + 10485760);    // 2 MB
  unsigned short* Wvb = (unsigned short*)(ws + 12582912);    // 2 MB
  unsigned short* Wob = (unsigned short*)(ws + 14680064);    // 2 MB
  unsigned short* Qb  = (unsigned short*)(ws + 16777216);    // 8 MB [B,H,S,D]
  unsigned short* Kbb = (unsigned short*)(ws + 25165824);    // 8 MB [B,H,S,D]
  unsigned short* Vtb = (unsigned short*)(ws + 33554432);    // 8 MB [B,H,D,S]
  unsigned short* Ab  = (unsigned short*)(ws + 41943040);    // 8 MB [B,S,E]

  cvt_all<<<dim3(8192), dim3(256), 0, stream>>>(x, Wq, Wk, Wv, Wo, xb, Wqb, Wkb, Wvb, Wob);
  qkv_gemm<<<dim3(32, 8, 3), dim3(256), 0, stream>>>(xb, Wqb, Wkb, Wvb, bq, bk, bv, Qb, Kbb, Vtb);
  attn_kernel<<<dim3(32, 16), dim3(512), 0, stream>>>(Qb, Kbb, Vtb, mask, Ab);
  out_gemm<<<dim3(64, 8), dim3(256), 0, stream>>>(Ab, Wob, bo, out);
}